// Round 2
// baseline (368.200 us; speedup 1.0000x reference)
//
#include <hip/hip_runtime.h>
#include <cmath>

#define B_   64
#define LX_  1024
#define LY_  1024
#define D_   300
#define DP   320      // padded K / e dimension
#define DV   304      // padded d for PV (19 * 16)
#define BM   64       // s-tile rows per block (flash attn)
#define KV   32       // t-tile

using f32x4  = __attribute__((ext_vector_type(4))) float;
using bf16x8 = __attribute__((ext_vector_type(8))) __bf16;
using u32x4  = __attribute__((ext_vector_type(4))) unsigned int;

static __device__ __forceinline__ unsigned short f2b(float f){
    unsigned u = __builtin_bit_cast(unsigned, f);
    u += 0x7FFFu + ((u >> 16) & 1u);          // round-to-nearest-even
    return (unsigned short)(u >> 16);
}

static __device__ __forceinline__ bf16x8 ld_bf8(const unsigned short* p){
    u32x4 u = *(const u32x4*)p;
    return __builtin_bit_cast(bf16x8, u);
}

static __device__ __forceinline__ f32x4 mfma16(bf16x8 a, bf16x8 b, f32x4 c){
    return __builtin_amdgcn_mfma_f32_16x16x32_bf16(a, b, c, 0, 0, 0);
}

// ---------------- K0: W (300x300 f32) -> Wb (320x320 bf16, zero padded) ----
__global__ void k_wconv(const float* __restrict__ W, unsigned short* __restrict__ Wb){
    int i = blockIdx.x * 256 + threadIdx.x;
    if (i >= DP * DP) return;
    int e = i / DP, d = i % DP;
    float v = (e < D_ && d < D_) ? W[e * D_ + d] : 0.f;
    Wb[i] = f2b(v);
}

// ---------------- K2: y (b,t,d f32) -> yT (b,d,t bf16), d padded to 304 ----
__global__ __launch_bounds__(256) void k_ytrans(const float* __restrict__ Y,
                                                unsigned short* __restrict__ yT){
    __shared__ float tile[64][65];
    const int bid = blockIdx.x;           // 64 * 16 * 5
    const int b  = bid / 80;
    const int tt = (bid % 80) / 5;
    const int dt = bid % 5;
    const int t0 = tt * 64, d0 = dt * 64;
    const int tid = threadIdx.x;
    const int dl = tid & 63, qq = tid >> 6;
    #pragma unroll
    for (int r = 0; r < 16; ++r){
        const int tl = qq * 16 + r;
        const int d = d0 + dl;
        float v = (d < D_) ? Y[((long)b * LY_ + t0 + tl) * D_ + d] : 0.f;
        tile[tl][dl] = v;
    }
    __syncthreads();
    #pragma unroll
    for (int r = 0; r < 16; ++r){
        const int drow = d0 + qq * 16 + r;
        if (drow < DV){
            float v = (drow < D_) ? tile[dl][qq * 16 + r] : 0.f;
            yT[((long)b * DV + drow) * LY_ + t0 + dl] = f2b(v);
        }
    }
}

// ---------------- K1: proj = relu(Z @ W^T + b) for Z = concat(x,y) ---------
// M = 131072 rows, 128 rows/block, 4 waves x (2 x 16-row subtiles)
__global__ __launch_bounds__(256) void k_proj(const float* __restrict__ X,
        const float* __restrict__ Y, const float* __restrict__ bias,
        const unsigned short* __restrict__ Wb,
        unsigned short* __restrict__ Px, unsigned short* __restrict__ Py){
    const int tid = threadIdx.x;
    const int w = tid >> 6, l = tid & 63;
    const int lr = l & 15, lg = l >> 4;
    const long m0 = (long)blockIdx.x * 128;
    const bool isX = (m0 < (long)B_ * LX_);
    const float* S = isX ? X : Y;
    unsigned short* Dst = isX ? Px : Py;
    const long base = isX ? m0 : m0 - (long)B_ * LX_;

    u32x4 a[2][10];
    #pragma unroll
    for (int ms = 0; ms < 2; ++ms){
        const float* rp = S + (base + 32 * w + 16 * ms + lr) * D_;
        #pragma unroll
        for (int ks = 0; ks < 10; ++ks){
            const int k0 = ks * 32 + lg * 8;
            f32x4 v0 = {0,0,0,0}, v1 = {0,0,0,0};
            if (k0 + 4 <= D_) v0 = *(const f32x4*)(rp + k0);
            if (k0 + 8 <= D_) v1 = *(const f32x4*)(rp + k0 + 4);
            u32x4 u;
            u[0] = (unsigned)f2b(v0[0]) | ((unsigned)f2b(v0[1]) << 16);
            u[1] = (unsigned)f2b(v0[2]) | ((unsigned)f2b(v0[3]) << 16);
            u[2] = (unsigned)f2b(v1[0]) | ((unsigned)f2b(v1[1]) << 16);
            u[3] = (unsigned)f2b(v1[2]) | ((unsigned)f2b(v1[3]) << 16);
            a[ms][ks] = u;
        }
    }

    #pragma unroll 1
    for (int es = 0; es < 20; ++es){
        f32x4 acc0 = {0,0,0,0}, acc1 = {0,0,0,0};
        const unsigned short* wp = Wb + (es * 16 + lr) * DP + lg * 8;
        #pragma unroll
        for (int ks = 0; ks < 10; ++ks){
            bf16x8 bf = ld_bf8(wp + ks * 32);
            acc0 = mfma16(__builtin_bit_cast(bf16x8, a[0][ks]), bf, acc0);
            acc1 = mfma16(__builtin_bit_cast(bf16x8, a[1][ks]), bf, acc1);
        }
        const int e = es * 16 + lr;
        const float bv = (e < D_) ? bias[e] : 0.f;
        #pragma unroll
        for (int r = 0; r < 4; ++r){
            float v0 = acc0[r] + bv; v0 = v0 > 0.f ? v0 : 0.f;
            float v1 = acc1[r] + bv; v1 = v1 > 0.f ? v1 : 0.f;
            Dst[(base + 32 * w + lg * 4 + r) * DP + e]      = f2b(v0);
            Dst[(base + 32 * w + 16 + lg * 4 + r) * DP + e] = f2b(v1);
        }
    }
}

// ---------------- K3: flash attention ---------------------------------------
// mask is int32 (harness converts bool -> int): 0 = keep, nonzero = masked out
__global__ __launch_bounds__(256, 2) void k_attn(const int* __restrict__ mask,
        const unsigned short* __restrict__ Px, const unsigned short* __restrict__ Py,
        const unsigned short* __restrict__ yT, float* __restrict__ out){
    __shared__ unsigned short Yp_lds[KV][328];   // padded stride: 2-way-only conflicts
    __shared__ unsigned short yT_lds[DV][40];
    __shared__ unsigned short P_lds[BM][40];

    const int tid = threadIdx.x;
    const int w = tid >> 6, l = tid & 63;
    const int lr = l & 15, lg = l >> 4;

    // XCD-bijective swizzle: all 16 s-blocks of a batch land on one XCD
    const int bid = blockIdx.x;              // 1024
    const int xcd = bid & 7;
    const int g = bid >> 3;
    const int b = xcd + 8 * (g >> 4);
    const int s0 = (g & 15) * BM;

    // Q fragments: wave w owns rows s0+16w .. s0+16w+15, all K in registers
    u32x4 q[10];
    {
        const unsigned short* qp = Px + ((long)b * LX_ + s0 + 16 * w + lr) * DP + lg * 8;
        #pragma unroll
        for (int ks = 0; ks < 10; ++ks) q[ks] = *(const u32x4*)(qp + ks * 32);
    }

    f32x4 acc[19];
    #pragma unroll
    for (int n = 0; n < 19; ++n) acc[n] = f32x4{0,0,0,0};
    float m_r[4] = {-INFINITY, -INFINITY, -INFINITY, -INFINITY};
    float l_r[4] = {0.f, 0.f, 0.f, 0.f};

    const int* mrow = mask + (long)b * LY_;

    for (int t0 = 0; t0 < LY_; t0 += KV){
        const int mv0 = (mrow[t0 + lr]      != 0) ? 1 : 0;
        const int mv1 = (mrow[t0 + 16 + lr] != 0) ? 1 : 0;
        if (__all(mv0 & mv1)) continue;     // tile fully masked (uniform)

        // stage Yp tile: 32 x 320 bf16 = 1280 16B-chunks
        #pragma unroll
        for (int j = 0; j < 5; ++j){
            const int id = tid + 256 * j;
            const int row = id / 40, c = id % 40;
            u32x4 v = *(const u32x4*)(Py + ((long)b * LY_ + t0 + row) * DP + c * 8);
            *(u32x4*)&Yp_lds[row][c * 8] = v;
        }
        // stage yT tile: 304 x 32 bf16 = 1216 16B-chunks
        #pragma unroll
        for (int j = 0; j < 5; ++j){
            const int id = tid + 256 * j;
            if (id < DV * 4){
                const int row = id >> 2, c = id & 3;
                u32x4 v = *(const u32x4*)(yT + ((long)b * DV + row) * LY_ + t0 + c * 8);
                *(u32x4*)&yT_lds[row][c * 8] = v;
            }
        }
        __syncthreads();

        // S = Q @ Yp^T : two 16x16 t-subtiles, K = 320
        f32x4 sv0 = {0,0,0,0}, sv1 = {0,0,0,0};
        #pragma unroll
        for (int ks = 0; ks < 10; ++ks){
            bf16x8 av = __builtin_bit_cast(bf16x8, q[ks]);
            bf16x8 b0 = ld_bf8(&Yp_lds[lr][ks * 32 + lg * 8]);
            bf16x8 b1 = ld_bf8(&Yp_lds[16 + lr][ks * 32 + lg * 8]);
            sv0 = mfma16(av, b0, sv0);
            sv1 = mfma16(av, b1, sv1);
        }

        // online softmax (rows = lg*4+r, cols across lanes 0..15 of group)
        const float sa0 = mv0 ? -3.0e38f : 0.f;
        const float sa1 = mv1 ? -3.0e38f : 0.f;
        float p0[4], p1[4], scl[4];
        #pragma unroll
        for (int r = 0; r < 4; ++r){
            const float v0 = sv0[r] + sa0;
            const float v1 = sv1[r] + sa1;
            float mx = fmaxf(v0, v1);
            mx = fmaxf(mx, __shfl_xor(mx, 1));
            mx = fmaxf(mx, __shfl_xor(mx, 2));
            mx = fmaxf(mx, __shfl_xor(mx, 4));
            mx = fmaxf(mx, __shfl_xor(mx, 8));
            const float nm = fmaxf(m_r[r], mx);
            const float e0 = __expf(v0 - nm);
            const float e1 = __expf(v1 - nm);
            float ps = e0 + e1;
            ps += __shfl_xor(ps, 1);
            ps += __shfl_xor(ps, 2);
            ps += __shfl_xor(ps, 4);
            ps += __shfl_xor(ps, 8);
            const float sc = __expf(m_r[r] - nm);   // first tile: exp(-inf)=0
            l_r[r] = l_r[r] * sc + ps;
            m_r[r] = nm;
            scl[r] = sc;
            p0[r] = e0; p1[r] = e1;
        }
        #pragma unroll
        for (int n = 0; n < 19; ++n){
            #pragma unroll
            for (int r = 0; r < 4; ++r) acc[n][r] *= scl[r];
        }

        // P -> LDS (bf16) for the PV A-fragment transpose
        const int prow = 16 * w + lg * 4;
        #pragma unroll
        for (int r = 0; r < 4; ++r){
            P_lds[prow + r][lr]      = f2b(p0[r]);
            P_lds[prow + r][16 + lr] = f2b(p1[r]);
        }
        __syncthreads();

        // O += P @ y : K = 32 (one MFMA step), 19 d-subtiles
        bf16x8 pf = ld_bf8(&P_lds[16 * w + lr][lg * 8]);
        #pragma unroll
        for (int n = 0; n < 19; ++n){
            bf16x8 vf = ld_bf8(&yT_lds[n * 16 + lr][lg * 8]);
            acc[n] = mfma16(pf, vf, acc[n]);
        }
        __syncthreads();   // before next iteration's staging overwrites
    }

    float inv[4];
    #pragma unroll
    for (int r = 0; r < 4; ++r) inv[r] = 1.f / l_r[r];
    #pragma unroll
    for (int n = 0; n < 19; ++n){
        const int d = n * 16 + lr;
        if (d < D_){
            #pragma unroll
            for (int r = 0; r < 4; ++r){
                out[((long)b * LX_ + s0 + 16 * w + lg * 4 + r) * D_ + d] = acc[n][r] * inv[r];
            }
        }
    }
}

extern "C" void kernel_launch(void* const* d_in, const int* in_sizes, int n_in,
                              void* d_out, int out_size, void* d_ws, size_t ws_size,
                              hipStream_t stream){
    const float* x = (const float*)d_in[0];
    const float* y = (const float*)d_in[1];
    const int* ymask = (const int*)d_in[2];
    const float* W = (const float*)d_in[3];
    const float* bias = (const float*)d_in[4];
    float* out = (float*)d_out;

    // workspace layout (needs ~118.3 MiB)
    unsigned short* Wb  = (unsigned short*)d_ws;                               // 204,800 B
    unsigned short* Px  = (unsigned short*)((char*)d_ws + (1 << 18));          // 41,943,040 B
    unsigned short* Py  = (unsigned short*)((char*)d_ws + (1 << 18) + 41943040LL);
    unsigned short* yTw = (unsigned short*)((char*)d_ws + (1 << 18) + 83886080LL);

    hipLaunchKernelGGL(k_wconv, dim3((DP * DP + 255) / 256), dim3(256), 0, stream, W, Wb);
    hipLaunchKernelGGL(k_proj,  dim3(1024), dim3(256), 0, stream, x, y, bias, Wb, Px, Py);
    hipLaunchKernelGGL(k_ytrans, dim3(64 * 80), dim3(256), 0, stream, y, yTw);
    hipLaunchKernelGGL(k_attn,  dim3(1024), dim3(256), 0, stream, ymask, Px, Py, yTw, out);
}